// Round 9
// baseline (764.557 us; speedup 1.0000x reference)
//
#include <hip/hip_runtime.h>
#include <cstdint>

#define SLOPE 0.33f

static constexpr int B_   = 64;
static constexpr int E1_  = 8978;
static constexpr int E2_  = 4489;
static constexpr int N1_  = B_ * E1_;      // 574592
static constexpr int N2_  = B_ * E2_;      // 287296
static constexpr int DEG_ = 16;
static constexpr int QTR_ = 2245;          // ceil(E1_/4)
static constexpr int QTR2_ = 1123;         // ceil(E2_/4)
static constexpr int MVGRID = (N2_ * 32) / 256;   // 35912 (exact)
static constexpr int HP_BLOCKS = 4489;            // logical blocks (64 nodes each)
static constexpr int HP_PERXCD = 562;             // ceil(4489/8)
static constexpr int HP_GRID = HP_PERXCD * 8;     // 4496 launched (7 idle)
static constexpr double EPS_ = 1e-5;

__device__ __forceinline__ float lrelu(float v) { return v > 0.f ? v : SLOPE * v; }
__device__ __forceinline__ float dot4(float4 a, float4 b) {
  return a.x * b.x + a.y * b.y + a.z * b.z + a.w * b.w;
}

// clang-native vector aliases for __builtin_nontemporal_load (HIP_vector_type rejected)
typedef float nf4 __attribute__((ext_vector_type(4)));
typedef int   ni4 __attribute__((ext_vector_type(4)));

__device__ __forceinline__ float4 ntload_f4(const float4* p) {
  nf4 v = __builtin_nontemporal_load((const nf4*)p);
  return make_float4(v.x, v.y, v.z, v.w);
}
__device__ __forceinline__ int4 ntload_i4(const int4* p) {
  ni4 v = __builtin_nontemporal_load((const ni4*)p);
  return make_int4(v.x, v.y, v.z, v.w);
}

// =====================================================================
// Layer 0: 1 channel. Per-graph x slab staged in LDS; edges of node g are
// [g*16, g*16+16) by construction (dst sorted). grid = 64 graphs * 4 quarters.
// =====================================================================
__global__ __launch_bounds__(256) void k0_mv1(const float* __restrict__ x,
    const int* __restrict__ src, const float* __restrict__ ew, float* __restrict__ T1) {
  __shared__ float sx[E1_];
  int g = blockIdx.x >> 2, q = blockIdx.x & 3;
  int gbase = g * E1_;
  for (int j = threadIdx.x; j < E1_; j += 256) sx[j] = x[gbase + j];
  __syncthreads();
  int start = q * QTR_, end = min(start + QTR_, E1_);
  for (int i = start + (int)threadIdx.x; i < end; i += 256) {
    int node = gbase + i;
    const int4* s4 = (const int4*)(src + (size_t)node * DEG_);
    const float4* w4 = (const float4*)(ew + (size_t)node * DEG_);
    float acc = 0.f;
#pragma unroll
    for (int j = 0; j < 4; ++j) {
      int4 s = s4[j]; float4 w = w4[j];
      acc += w.x * sx[s.x - gbase] + w.y * sx[s.y - gbase]
           + w.z * sx[s.z - gbase] + w.w * sx[s.w - gbase];
    }
    T1[node] = sx[i] - acc;   // T1 = x - L x
  }
}

__global__ __launch_bounds__(256) void k0_mv2(const float* __restrict__ x,
    const int* __restrict__ src, const float* __restrict__ ew,
    const float* __restrict__ T1, float* __restrict__ T2) {
  __shared__ float sT[E1_];
  int g = blockIdx.x >> 2, q = blockIdx.x & 3;
  int gbase = g * E1_;
  for (int j = threadIdx.x; j < E1_; j += 256) sT[j] = T1[gbase + j];
  __syncthreads();
  int start = q * QTR_, end = min(start + QTR_, E1_);
  for (int i = start + (int)threadIdx.x; i < end; i += 256) {
    int node = gbase + i;
    const int4* s4 = (const int4*)(src + (size_t)node * DEG_);
    const float4* w4 = (const float4*)(ew + (size_t)node * DEG_);
    float acc = 0.f;
#pragma unroll
    for (int j = 0; j < 4; ++j) {
      int4 s = s4[j]; float4 w = w4[j];
      acc += w.x * sT[s.x - gbase] + w.y * sT[s.y - gbase]
           + w.z * sT[s.z - gbase] + w.w * sT[s.w - gbase];
    }
    T2[node] = (3.f * sT[i] - acc - x[node]) * 0.5f;  // T2 = (3T1 - L T1 - T0)/2
  }
}

// T3 = (5T2 - L T2 - 2T1)/3, plus moment accumulation for layer-0 BN.
__global__ __launch_bounds__(256) void k0_mv3(const float* __restrict__ x,
    const int* __restrict__ src, const float* __restrict__ ew,
    const float* __restrict__ T1, const float* __restrict__ T2,
    float* __restrict__ T3, double* mom) {
  __shared__ float sT[E1_];
  __shared__ double sred[4 * 14];
  int g = blockIdx.x >> 2, q = blockIdx.x & 3;
  int gbase = g * E1_;
  for (int j = threadIdx.x; j < E1_; j += 256) sT[j] = T2[gbase + j];
  __syncthreads();
  double m[14];
#pragma unroll
  for (int j = 0; j < 14; ++j) m[j] = 0.0;
  int start = q * QTR_, end = min(start + QTR_, E1_);
  for (int i = start + (int)threadIdx.x; i < end; i += 256) {
    int node = gbase + i;
    const int4* s4 = (const int4*)(src + (size_t)node * DEG_);
    const float4* w4 = (const float4*)(ew + (size_t)node * DEG_);
    float acc = 0.f;
#pragma unroll
    for (int j = 0; j < 4; ++j) {
      int4 s = s4[j]; float4 w = w4[j];
      acc += w.x * sT[s.x - gbase] + w.y * sT[s.y - gbase]
           + w.z * sT[s.z - gbase] + w.w * sT[s.w - gbase];
    }
    float t1 = T1[node];
    float t2 = sT[i];
    float t3 = (5.f * t2 - acc - 2.f * t1) * (1.f / 3.f);
    T3[node] = t3;
    double d0 = x[node], d1 = t1, d2 = t2, d3 = t3;
    m[0] += d0; m[1] += d1; m[2] += d2; m[3] += d3;
    m[4] += d0 * d0; m[5] += d0 * d1; m[6] += d0 * d2; m[7] += d0 * d3;
    m[8] += d1 * d1; m[9] += d1 * d2; m[10] += d1 * d3;
    m[11] += d2 * d2; m[12] += d2 * d3; m[13] += d3 * d3;
  }
  int lane = threadIdx.x & 63, wid = threadIdx.x >> 6;
#pragma unroll
  for (int j = 0; j < 14; ++j) {
    double v = m[j];
    for (int o = 32; o; o >>= 1) v += __shfl_down(v, o);
    if (lane == 0) sred[wid * 14 + j] = v;
  }
  __syncthreads();
  if (threadIdx.x < 14) {
    double s = sred[threadIdx.x] + sred[14 + threadIdx.x] + sred[28 + threadIdx.x] + sred[42 + threadIdx.x];
    atomicAdd(&mom[threadIdx.x], s);
  }
}

// BN params for layer 0 (b0 cancels in BN exactly).
__global__ void k0_params(const double* __restrict__ mom, const float* __restrict__ W0,
    const float* __restrict__ g0, const float* __restrict__ be0,
    float* __restrict__ scale0, float* __restrict__ shiftE0) {
  int c = threadIdx.x;
  if (c >= 32) return;
  double inv = 1.0 / (double)N1_;
  double mm[4];
#pragma unroll
  for (int k = 0; k < 4; ++k) mm[k] = mom[k] * inv;
  double M[4][4];
  M[0][0] = mom[4] * inv;  M[0][1] = mom[5] * inv;  M[0][2] = mom[6] * inv;  M[0][3] = mom[7] * inv;
  M[1][1] = mom[8] * inv;  M[1][2] = mom[9] * inv;  M[1][3] = mom[10] * inv;
  M[2][2] = mom[11] * inv; M[2][3] = mom[12] * inv; M[3][3] = mom[13] * inv;
  M[1][0] = M[0][1]; M[2][0] = M[0][2]; M[3][0] = M[0][3];
  M[2][1] = M[1][2]; M[3][1] = M[1][3]; M[3][2] = M[2][3];
  double w[4];
#pragma unroll
  for (int k = 0; k < 4; ++k) w[k] = W0[k * 32 + c];
  double mean = 0.0;
#pragma unroll
  for (int k = 0; k < 4; ++k) mean += w[k] * mm[k];
  double e2 = 0.0;
#pragma unroll
  for (int k = 0; k < 4; ++k)
#pragma unroll
    for (int l = 0; l < 4; ++l) e2 += M[k][l] * w[k] * w[l];
  double var = e2 - mean * mean;
  double sc = (double)g0[c] / sqrt(var + EPS_);
  scale0[c] = (float)sc;
  shiftE0[c] = (float)((double)be0[c] - sc * mean);
}

// fused: project to 32ch + BN + LeakyReLU + Graclus pair-max pool -> x1 (N2,32)
__global__ __launch_bounds__(256) void k0_pool(const float* __restrict__ x,
    const float* __restrict__ T1, const float* __restrict__ T2, const float* __restrict__ T3,
    const float* __restrict__ W0, const float* __restrict__ scale0,
    const float* __restrict__ shiftE0, float* __restrict__ x1) {
  int gid = blockIdx.x * 256 + threadIdx.x;
  int grp = gid >> 5, c = gid & 31;
  if (grp >= N2_) return;
  int b = grp / E2_, j = grp - b * E2_;
  int ga = b * E1_ + 2 * j, gb = ga + 1;
  float w0 = W0[c], w1 = W0[32 + c], w2 = W0[64 + c], w3 = W0[96 + c];
  float da = x[ga] * w0 + T1[ga] * w1 + T2[ga] * w2 + T3[ga] * w3;
  float db = x[gb] * w0 + T1[gb] * w1 + T2[gb] * w2 + T3[gb] * w3;
  float sc = scale0[c], sh = shiftE0[c];
  float ya = lrelu(sc * da + sh), yb = lrelu(sc * db + sh);
  x1[grp * 32 + c] = fmaxf(ya, yb);
}

// =====================================================================
// Layer-1 Horner with fused self-projection:
//   out1 = P0 + L(P1 + L(P2 + L P3)),  P_j = x1 @ Q_j.
// mv_hp: O[n] = x1[n] @ Q + (L G)[n]   (G == nullptr -> pure projection)
// XCD-aware swizzle gives each XCD a contiguous ~8-graph range (R6: FETCH
// 199->55 MB). Stream-once data (edge lists, x1 self-rows) use NONTEMPORAL
// loads so they don't evict gather (G) lines from the 4 MB per-XCD L2.
// =====================================================================
__global__ __launch_bounds__(256) void mv_hp(const float* __restrict__ X,
    const float* __restrict__ G, const int* __restrict__ src,
    const float* __restrict__ ew, const float* __restrict__ W1,
    float4 cf, float* __restrict__ O) {
  __shared__ float4 Q[8 * 33];   // [c4][t*4+k], row pad 33 -> phase conflict-free
  {
    int e = threadIdx.x;         // 256 entries, one per thread
    int c4 = e >> 5, r = e & 31;
    int t = r >> 2, k = r & 3;
    int out = c4 * 4 + k;
    const float* wp = W1 + (4 * t) * 32 + out;   // W1[K][inp][out]
    float4 w;
    w.x = cf.x * wp[0]  + cf.y * wp[1024]      + cf.z * wp[2048]      + cf.w * wp[3072];
    w.y = cf.x * wp[32] + cf.y * wp[1024 + 32] + cf.z * wp[2048 + 32] + cf.w * wp[3072 + 32];
    w.z = cf.x * wp[64] + cf.y * wp[1024 + 64] + cf.z * wp[2048 + 64] + cf.w * wp[3072 + 64];
    w.w = cf.x * wp[96] + cf.y * wp[1024 + 96] + cf.z * wp[2048 + 96] + cf.w * wp[3072 + 96];
    Q[c4 * 33 + r] = w;
  }
  __syncthreads();
  int v = (blockIdx.x & 7) * HP_PERXCD + (blockIdx.x >> 3);
  if (v >= HP_BLOCKS) return;
  int pid = v * 256 + threadIdx.x;
  int c4 = pid & 7, npair = pid >> 3;
  int n0 = npair * 2, n1 = n0 + 1;
  const float4* p0 = (const float4*)(X + (size_t)n0 * 32);
  const float4* p1 = (const float4*)(X + (size_t)n1 * 32);
  float4 x0[8], x1r[8];
#pragma unroll
  for (int t = 0; t < 8; ++t) {
    x0[t] = ntload_f4(&p0[t]);
    x1r[t] = ntload_f4(&p1[t]);
  }
  float4 a0 = {0.f, 0.f, 0.f, 0.f}, a1 = {0.f, 0.f, 0.f, 0.f};
  const float4* Qc = Q + c4 * 33;
#pragma unroll
  for (int t = 0; t < 8; ++t) {
    float4 w0 = Qc[t * 4 + 0];
    float4 w1 = Qc[t * 4 + 1];
    float4 w2 = Qc[t * 4 + 2];
    float4 w3 = Qc[t * 4 + 3];
    float4 xv0 = x0[t], xv1 = x1r[t];
    a0.x += dot4(xv0, w0); a0.y += dot4(xv0, w1); a0.z += dot4(xv0, w2); a0.w += dot4(xv0, w3);
    a1.x += dot4(xv1, w0); a1.y += dot4(xv1, w1); a1.z += dot4(xv1, w2); a1.w += dot4(xv1, w3);
  }
  if (G != nullptr) {
    const float4* G4 = (const float4*)G;
    {
      const int4* s4 = (const int4*)(src + (size_t)n0 * DEG_);
      const float4* w4 = (const float4*)(ew + (size_t)n0 * DEG_);
#pragma unroll
      for (int j = 0; j < 4; ++j) {
        int4 s = ntload_i4(&s4[j]);
        float4 w = ntload_f4(&w4[j]);
        float4 ga = G4[(size_t)s.x * 8 + c4];
        float4 gb = G4[(size_t)s.y * 8 + c4];
        float4 gc = G4[(size_t)s.z * 8 + c4];
        float4 gd = G4[(size_t)s.w * 8 + c4];
        a0.x += w.x * ga.x + w.y * gb.x + w.z * gc.x + w.w * gd.x;
        a0.y += w.x * ga.y + w.y * gb.y + w.z * gc.y + w.w * gd.y;
        a0.z += w.x * ga.z + w.y * gb.z + w.z * gc.z + w.w * gd.z;
        a0.w += w.x * ga.w + w.y * gb.w + w.z * gc.w + w.w * gd.w;
      }
    }
    {
      const int4* s4 = (const int4*)(src + (size_t)n1 * DEG_);
      const float4* w4 = (const float4*)(ew + (size_t)n1 * DEG_);
#pragma unroll
      for (int j = 0; j < 4; ++j) {
        int4 s = ntload_i4(&s4[j]);
        float4 w = ntload_f4(&w4[j]);
        float4 ga = G4[(size_t)s.x * 8 + c4];
        float4 gb = G4[(size_t)s.y * 8 + c4];
        float4 gc = G4[(size_t)s.z * 8 + c4];
        float4 gd = G4[(size_t)s.w * 8 + c4];
        a1.x += w.x * ga.x + w.y * gb.x + w.z * gc.x + w.w * gd.x;
        a1.y += w.x * ga.y + w.y * gb.y + w.z * gc.y + w.w * gd.y;
        a1.z += w.x * ga.z + w.y * gb.z + w.z * gc.z + w.w * gd.z;
        a1.w += w.x * ga.w + w.y * gb.w + w.z * gc.w + w.w * gd.w;
      }
    }
  }
  *(float4*)(O + (size_t)n0 * 32 + c4 * 4) = a0;
  *(float4*)(O + (size_t)n1 * 32 + c4 * 4) = a1;
}

// per-channel sum/sumsq of a (N2,32) array (for layer-1 BN)
__global__ __launch_bounds__(256) void k_stats32(const float* __restrict__ X,
    double* sum, double* sq) {
  __shared__ double s1[256], s2[256];
  const long total = (long)N2_ * 32;
  double a = 0.0, b = 0.0;
  for (long idx = (long)blockIdx.x * 256 + threadIdx.x; idx < total; idx += (long)gridDim.x * 256) {
    double v = X[idx]; a += v; b += v * v;
  }
  s1[threadIdx.x] = a; s2[threadIdx.x] = b;
  __syncthreads();
  int c = threadIdx.x;
  if (c < 32) {
    double sa = 0.0, sb = 0.0;
    for (int j = c; j < 256; j += 32) { sa += s1[j]; sb += s2[j]; }
    atomicAdd(&sum[c], sa); atomicAdd(&sq[c], sb);
  }
}

__global__ void k1_params(const double* __restrict__ sum, const double* __restrict__ sq,
    const float* __restrict__ g1, const float* __restrict__ be1,
    float* __restrict__ scale1, float* __restrict__ shiftE1) {
  int c = threadIdx.x;
  if (c >= 32) return;
  double mean = sum[c] / (double)N2_;
  double var = sq[c] / (double)N2_ - mean * mean;
  double sc = (double)g1[c] / sqrt(var + EPS_);
  scale1[c] = (float)sc;
  shiftE1[c] = (float)((double)be1[c] - sc * mean);
}

// =====================================================================
// Layer-2 Horner on 1-channel fields: u_j = f(out1) q_j (q_j from W2),
// out2 = u0 + L(u1 + L(u2 + L u3)).  b2 cancels in BN2.
// =====================================================================
__global__ __launch_bounds__(256) void k2_proj(const float* __restrict__ X,
    const float* __restrict__ W2, const float* __restrict__ scale1,
    const float* __restrict__ shiftE1,
    float* __restrict__ u0, float* __restrict__ u1,
    float* __restrict__ u2, float* __restrict__ u3) {
  __shared__ float qv[4][32];
  __shared__ float fsc[32], fsh[32];
  int tid = threadIdx.x;
  if (tid < 128) {
    int cp = tid & 31, j = tid >> 5;
    float w0 = W2[cp], w1 = W2[32 + cp], w2 = W2[64 + cp], w3 = W2[96 + cp];
    float q;
    if (j == 0)      q = w0 + w1 + w2 + w3;
    else if (j == 1) q = -w1 - 2.f * w2 - 3.f * w3;
    else if (j == 2) q = 0.5f * w2 + 1.5f * w3;
    else             q = -w3 * (1.f / 6.f);
    qv[j][cp] = q;
  }
  if (tid < 32) { fsc[tid] = scale1[tid]; fsh[tid] = shiftE1[tid]; }
  __syncthreads();
  int node = blockIdx.x * 256 + tid;
  if (node >= N2_) return;
  const float4* xr = (const float4*)(X + (size_t)node * 32);
  float a0 = 0.f, a1 = 0.f, a2 = 0.f, a3 = 0.f;
#pragma unroll
  for (int t = 0; t < 8; ++t) {
    float4 v = xr[t];
    float f0 = lrelu(fsc[4 * t] * v.x + fsh[4 * t]);
    float f1 = lrelu(fsc[4 * t + 1] * v.y + fsh[4 * t + 1]);
    float f2_ = lrelu(fsc[4 * t + 2] * v.z + fsh[4 * t + 2]);
    float f3 = lrelu(fsc[4 * t + 3] * v.w + fsh[4 * t + 3]);
    a0 += f0 * qv[0][4 * t] + f1 * qv[0][4 * t + 1] + f2_ * qv[0][4 * t + 2] + f3 * qv[0][4 * t + 3];
    a1 += f0 * qv[1][4 * t] + f1 * qv[1][4 * t + 1] + f2_ * qv[1][4 * t + 2] + f3 * qv[1][4 * t + 3];
    a2 += f0 * qv[2][4 * t] + f1 * qv[2][4 * t + 1] + f2_ * qv[2][4 * t + 2] + f3 * qv[2][4 * t + 3];
    a3 += f0 * qv[3][4 * t] + f1 * qv[3][4 * t + 1] + f2_ * qv[3][4 * t + 2] + f3 * qv[3][4 * t + 3];
  }
  u0[node] = a0; u1[node] = a1; u2[node] = a2; u3[node] = a3;
}

// k2_step: zo = u + L z (1-channel), per-graph z slab in LDS.
// grid = 64 graphs x 4 quarters. do_stats!=0: also global sum/sumsq of zo.
__global__ __launch_bounds__(256) void k2_step(const float* __restrict__ z,
    const int* __restrict__ src, const float* __restrict__ ew,
    const float* __restrict__ u, float* __restrict__ zo,
    int do_stats, double* st2) {
  __shared__ float sz[E2_];
  __shared__ double sred[4][2];
  int g = blockIdx.x >> 2, q = blockIdx.x & 3;
  int gbase = g * E2_;
  for (int j = threadIdx.x; j < E2_; j += 256) sz[j] = z[gbase + j];
  __syncthreads();
  int start = q * QTR2_, end = min(start + QTR2_, E2_);
  double aS = 0.0, aQ = 0.0;
  for (int i = start + (int)threadIdx.x; i < end; i += 256) {
    int node = gbase + i;
    const int4* s4 = (const int4*)(src + (size_t)node * DEG_);
    const float4* w4 = (const float4*)(ew + (size_t)node * DEG_);
    float acc = 0.f;
#pragma unroll
    for (int j = 0; j < 4; ++j) {
      int4 s = s4[j]; float4 w = w4[j];
      acc += w.x * sz[s.x - gbase] + w.y * sz[s.y - gbase]
           + w.z * sz[s.z - gbase] + w.w * sz[s.w - gbase];
    }
    float val = u[node] + acc;
    zo[node] = val;
    if (do_stats) { aS += val; aQ += (double)val * (double)val; }
  }
  if (do_stats) {
    int lane = threadIdx.x & 63, wid = threadIdx.x >> 6;
    for (int o = 32; o; o >>= 1) { aS += __shfl_down(aS, o); aQ += __shfl_down(aQ, o); }
    if (lane == 0) { sred[wid][0] = aS; sred[wid][1] = aQ; }
    __syncthreads();
    if (threadIdx.x == 0) {
      double s = sred[0][0] + sred[1][0] + sred[2][0] + sred[3][0];
      double qq = sred[0][1] + sred[1][1] + sred[2][1] + sred[3][1];
      atomicAdd(&st2[0], s); atomicAdd(&st2[1], qq);
    }
  }
}

__global__ void k2_params(const double* __restrict__ st2, const float* __restrict__ g2,
    const float* __restrict__ be2, float* __restrict__ p /* [128]=scale2 [129]=shiftE2 */) {
  if (threadIdx.x != 0) return;
  double mean = st2[0] / (double)N2_;
  double var = st2[1] / (double)N2_ - mean * mean;
  double sc = (double)g2[0] / sqrt(var + EPS_);
  p[128] = (float)sc;
  p[129] = (float)((double)be2[0] - sc * mean);
}

// MLP gemm1: h1pre[b,c] = sum_r f2(out2[b*E2+r]) * lin1_W[r,c]
__global__ __launch_bounds__(256) void k3_gemm1(const float* __restrict__ out2,
    const float* __restrict__ lin1W, const float* __restrict__ p, float* h1pre) {
  __shared__ float f2v[4][284];
  float sc = p[128], sh = p[129];
  int bs = blockIdx.x & 15, rs = blockIdx.x >> 4;
  int b0 = bs * 4;
  int r0 = rs * 281;
  int nr = min(281, E2_ - r0);
  int c = threadIdx.x;
#pragma unroll
  for (int b = 0; b < 4; ++b)
    for (int j = c; j < 284; j += 256)
      f2v[b][j] = (j < nr) ? lrelu(sc * out2[(b0 + b) * E2_ + r0 + j] + sh) : 0.f;
  __syncthreads();
  float acc0 = 0.f, acc1 = 0.f, acc2 = 0.f, acc3 = 0.f;
  int nr4 = nr & ~3;
  int j = 0;
  for (; j < nr4; j += 4) {
    const float* wp = lin1W + (size_t)(r0 + j) * 256 + c;
    float w0 = wp[0], w1 = wp[256], w2 = wp[512], w3 = wp[768];
    float4 f0 = *(const float4*)&f2v[0][j];
    float4 f1 = *(const float4*)&f2v[1][j];
    float4 f2_ = *(const float4*)&f2v[2][j];
    float4 f3 = *(const float4*)&f2v[3][j];
    acc0 += f0.x * w0 + f0.y * w1 + f0.z * w2 + f0.w * w3;
    acc1 += f1.x * w0 + f1.y * w1 + f1.z * w2 + f1.w * w3;
    acc2 += f2_.x * w0 + f2_.y * w1 + f2_.z * w2 + f2_.w * w3;
    acc3 += f3.x * w0 + f3.y * w1 + f3.z * w2 + f3.w * w3;
  }
  for (; j < nr; ++j) {
    float w = lin1W[(size_t)(r0 + j) * 256 + c];
    acc0 += f2v[0][j] * w;
    acc1 += f2v[1][j] * w;
    acc2 += f2v[2][j] * w;
    acc3 += f2v[3][j] * w;
  }
  atomicAdd(&h1pre[(b0 + 0) * 256 + c], acc0);
  atomicAdd(&h1pre[(b0 + 1) * 256 + c], acc1);
  atomicAdd(&h1pre[(b0 + 2) * 256 + c], acc2);
  atomicAdd(&h1pre[(b0 + 3) * 256 + c], acc3);
}

// BN1 + ReLU -> h1 (64,256)
__global__ __launch_bounds__(256) void k4_bn1(const float* __restrict__ h1pre,
    const float* __restrict__ g, const float* __restrict__ be, float* __restrict__ h1) {
  int c = threadIdx.x;
  float vs[64];
  double s = 0.0, q = 0.0;
  for (int b = 0; b < 64; ++b) { float v = h1pre[b * 256 + c]; vs[b] = v; s += v; q += (double)v * v; }
  double mean = s / 64.0, var = q / 64.0 - mean * mean;
  double scd = (double)g[c] / sqrt(var + EPS_);
  double shd = (double)be[c] - scd * mean;
  for (int b = 0; b < 64; ++b) {
    float y = (float)(scd * vs[b] + shd);
    h1[b * 256 + c] = y > 0.f ? y : 0.f;
  }
}

// gemm2: 128 blocks, block = output column
__global__ __launch_bounds__(256) void k5_gemm2(const float* __restrict__ h1,
    const float* __restrict__ lin2W, float* __restrict__ h2pre) {
  __shared__ float sred[256];
  int c = blockIdx.x;
  int b = threadIdx.x & 63, q = threadIdx.x >> 6;
  float acc = 0.f;
  for (int r = q; r < 256; r += 4) acc += h1[b * 256 + r] * lin2W[r * 128 + c];
  sred[threadIdx.x] = acc;
  __syncthreads();
  if (threadIdx.x < 64)
    h2pre[threadIdx.x * 128 + c] = sred[threadIdx.x] + sred[64 + threadIdx.x]
                                 + sred[128 + threadIdx.x] + sred[192 + threadIdx.x];
}

// BN2 + ReLU + final linear -> out[64]
__global__ __launch_bounds__(256) void k6_final(const float* __restrict__ h2pre,
    const float* __restrict__ g, const float* __restrict__ be,
    const float* __restrict__ W3, const float* __restrict__ b3, float* __restrict__ outp) {
  __shared__ float sh2[64 * 129];
  __shared__ float sred[256];
  int tid = threadIdx.x;
  if (tid < 128) {
    int c = tid;
    float vs[64];
    double s = 0.0, q = 0.0;
    for (int b = 0; b < 64; ++b) { float v = h2pre[b * 128 + c]; vs[b] = v; s += v; q += (double)v * v; }
    double mean = s / 64.0, var = q / 64.0 - mean * mean;
    double scd = (double)g[c] / sqrt(var + EPS_);
    double shd = (double)be[c] - scd * mean;
    for (int b = 0; b < 64; ++b) {
      float y = (float)(scd * vs[b] + shd);
      sh2[b * 129 + c] = y > 0.f ? y : 0.f;
    }
  }
  __syncthreads();
  int b = tid & 63, q = tid >> 6;
  float acc = 0.f;
  for (int r = q; r < 128; r += 4) acc += sh2[b * 129 + r] * W3[r];
  sred[tid] = acc;
  __syncthreads();
  if (tid < 64)
    outp[tid] = sred[tid] + sred[64 + tid] + sred[128 + tid] + sred[192 + tid] + b3[0];
}

// =====================================================================
extern "C" void kernel_launch(void* const* d_in, const int* in_sizes, int n_in,
                              void* d_out, int out_size, void* d_ws, size_t ws_size,
                              hipStream_t stream) {
  const float* x    = (const float*)d_in[0];
  const int*   ei1  = (const int*)d_in[1];
  const float* ew1  = (const float*)d_in[2];
  const int*   ei2  = (const int*)d_in[3];
  const float* ew2  = (const float*)d_in[4];
  const float* W0   = (const float*)d_in[5];
  const float* g0   = (const float*)d_in[7];
  const float* be0  = (const float*)d_in[8];
  const float* W1   = (const float*)d_in[9];
  const float* g1   = (const float*)d_in[11];
  const float* be1  = (const float*)d_in[12];
  const float* W2   = (const float*)d_in[13];
  const float* g2   = (const float*)d_in[15];
  const float* be2  = (const float*)d_in[16];
  const float* lin1W = (const float*)d_in[17];
  const float* bn1g = (const float*)d_in[19];
  const float* bn1b = (const float*)d_in[20];
  const float* lin2W = (const float*)d_in[21];
  const float* bn2g = (const float*)d_in[23];
  const float* bn2b = (const float*)d_in[24];
  const float* lin3W = (const float*)d_in[25];
  const float* lin3b = (const float*)d_in[26];

  char* ws = (char*)d_ws;
  double* stats  = (double*)ws;                 // [0..13] mom0, [14..45] s1sum, [46..77] s1sq, [78..79] st2
  float*  params = (float*)(ws + 1024);         // scale0[32] shiftE0[32] scale1[32] shiftE1[32] ... [128..129]
  float*  h1pre  = (float*)(ws + 4096);
  float*  h1     = (float*)(ws + 4096 + 65536);
  float*  h2pre  = (float*)(ws + 4096 + 131072);
  // Treg: 3*N1 floats. Layer-0 T arrays live here; later overlaid by u/z/out2
  float*  Treg   = (float*)(ws + 262144);
  float* T1_0 = Treg;
  float* T2_0 = Treg + N1_;
  float* T3_0 = Treg + 2 * (size_t)N1_;
  float* u0   = Treg;                           // overlays (T dead after k0_pool)
  float* u1   = Treg + (size_t)N2_;
  float* u2   = Treg + 2 * (size_t)N2_;
  float* u3   = Treg + 3 * (size_t)N2_;
  float* zA   = Treg + 4 * (size_t)N2_;
  float* out2 = Treg + 5 * (size_t)N2_;         // 6*N2 <= 3*N1  ✓
  float*  big = (float*)(ws + 262144 + 3 * (size_t)N1_ * 4);
  float* bufA = big;                            // x1 (live through all of layer 1)
  float* bufB = bufA + 32 * (size_t)N2_;        // P3, later out1
  float* bufC = bufB + 32 * (size_t)N2_;        // Z2
  float* bufD = bufC + 32 * (size_t)N2_;        // Z1

  hipMemsetAsync(stats, 0, 80 * sizeof(double), stream);
  hipMemsetAsync(h1pre, 0, 65536, stream);

  // ---- layer 0 ----
  k0_mv1<<<256, 256, 0, stream>>>(x, ei1, ew1, T1_0);
  k0_mv2<<<256, 256, 0, stream>>>(x, ei1, ew1, T1_0, T2_0);
  k0_mv3<<<256, 256, 0, stream>>>(x, ei1, ew1, T1_0, T2_0, T3_0, stats);
  k0_params<<<1, 32, 0, stream>>>(stats, W0, g0, be0, params, params + 32);
  k0_pool<<<MVGRID, 256, 0, stream>>>(x, T1_0, T2_0, T3_0, W0, params, params + 32, bufA);

  // ---- layer 1 (Horner, fused self-projection; only P3 materialized) ----
  float4 cQ3 = {0.f, 0.f, 0.f, -1.f / 6.f};
  float4 cQ2 = {0.f, 0.f, 0.5f, 1.5f};
  float4 cQ1 = {0.f, -1.f, -2.f, -3.f};
  float4 cQ0 = {1.f, 1.f, 1.f, 1.f};
  mv_hp<<<HP_GRID, 256, 0, stream>>>(bufA, nullptr, ei2, ew2, W1, cQ3, bufB); // P3 = x1@Q3
  mv_hp<<<HP_GRID, 256, 0, stream>>>(bufA, bufB, ei2, ew2, W1, cQ2, bufC);    // Z2 = x1@Q2 + L P3
  mv_hp<<<HP_GRID, 256, 0, stream>>>(bufA, bufC, ei2, ew2, W1, cQ1, bufD);    // Z1 = x1@Q1 + L Z2
  mv_hp<<<HP_GRID, 256, 0, stream>>>(bufA, bufD, ei2, ew2, W1, cQ0, bufB);    // out1 = x1@Q0 + L Z1
  k_stats32<<<2048, 256, 0, stream>>>(bufB, stats + 14, stats + 46);
  k1_params<<<1, 32, 0, stream>>>(stats + 14, stats + 46, g1, be1, params + 64, params + 96);

  // ---- layer 2 (Horner, 1-channel) ----
  k2_proj<<<(N2_ + 255) / 256, 256, 0, stream>>>(bufB, W2, params + 64, params + 96,
                                                 u0, u1, u2, u3);
  k2_step<<<256, 256, 0, stream>>>(u3, ei2, ew2, u2, zA, 0, nullptr);       // zA = u2 + L u3
  k2_step<<<256, 256, 0, stream>>>(zA, ei2, ew2, u1, u3, 0, nullptr);       // u3slot = u1 + L zA
  k2_step<<<256, 256, 0, stream>>>(u3, ei2, ew2, u0, out2, 1, stats + 78);  // out2 + stats
  k2_params<<<1, 64, 0, stream>>>(stats + 78, g2, be2, params);

  // ---- MLP head ----
  k3_gemm1<<<256, 256, 0, stream>>>(out2, lin1W, params, h1pre);
  k4_bn1<<<1, 256, 0, stream>>>(h1pre, bn1g, bn1b, h1);
  k5_gemm2<<<128, 256, 0, stream>>>(h1, lin2W, h2pre);
  k6_final<<<1, 256, 0, stream>>>(h2pre, bn2g, bn2b, lin3W, lin3b, (float*)d_out);
}